// Round 1
// baseline (1072.127 us; speedup 1.0000x reference)
//
#include <hip/hip_runtime.h>
#include <stdint.h>

typedef __attribute__((ext_vector_type(8))) short short8;   // 8 x bf16 (4 VGPRs)
typedef __attribute__((ext_vector_type(4))) float f32x4;    // MFMA accumulator

__device__ __forceinline__ unsigned short f2bf(float f) {
  union { float f; unsigned int u; } v;
  v.f = f;
  // round-to-nearest-even fp32 -> bf16
  return (unsigned short)((v.u + 0x7fffu + ((v.u >> 16) & 1u)) >> 16);
}

// async global->LDS, 16B per lane; LDS dest = wave-uniform base + lane*16
__device__ __forceinline__ void load16(const unsigned short* g, unsigned short* l) {
  __builtin_amdgcn_global_load_lds(
      (const __attribute__((address_space(1))) unsigned int*)g,
      (__attribute__((address_space(3))) unsigned int*)l, 16, 0, 0);
}

// ---------------- pass 1: fp32 -> bf16 convert (vectorized, grid-stride) ----
__global__ void convert_kernel(const float* __restrict__ in,
                               unsigned short* __restrict__ out, int n4) {
  int stride = gridDim.x * blockDim.x;
  for (int i = blockIdx.x * blockDim.x + threadIdx.x; i < n4; i += stride) {
    float4 v = reinterpret_cast<const float4*>(in)[i];
    ushort4 o;
    o.x = f2bf(v.x); o.y = f2bf(v.y); o.z = f2bf(v.z); o.w = f2bf(v.w);
    reinterpret_cast<ushort4*>(out)[i] = o;
  }
}

// ---------------- pass 2: t = SCALING * x @ lora_a^T (per adapter) ----------
// one wave per 16-row strip; MFMA 16x16x32, N=16, K=4096
__global__ void lora_t_kernel(const unsigned short* __restrict__ xb,
                              const float* __restrict__ lora_a,
                              unsigned short* __restrict__ tb) {
  const int t = threadIdx.x;
  const int lane = t & 63;
  const int w = t >> 6;
  const int quad = lane >> 4;
  const int m16 = lane & 15;
  const int r0 = (blockIdx.x * 4 + w) << 4;   // first row of this wave's strip
  const int a = r0 >> 11;                     // adapter = row / 2048
  const unsigned short* xrow = xb + (size_t)(r0 + m16) * 4096 + (quad << 3);
  const float* arow = lora_a + (size_t)(a * 16 + m16) * 4096 + (quad << 3);
  f32x4 acc = {0.f, 0.f, 0.f, 0.f};
  for (int k = 0; k < 4096; k += 32) {
    short8 af = *(const short8*)(xrow + k);          // A[m=lane&15][k=quad*8+j]
    float4 f0 = *(const float4*)(arow + k);          // B[n=lane&15][k=quad*8+j]
    float4 f1 = *(const float4*)(arow + k + 4);
    short8 bf;
    bf[0] = (short)f2bf(f0.x); bf[1] = (short)f2bf(f0.y);
    bf[2] = (short)f2bf(f0.z); bf[3] = (short)f2bf(f0.w);
    bf[4] = (short)f2bf(f1.x); bf[5] = (short)f2bf(f1.y);
    bf[6] = (short)f2bf(f1.z); bf[7] = (short)f2bf(f1.w);
    acc = __builtin_amdgcn_mfma_f32_16x16x32_bf16(af, bf, acc, 0, 0, 0);
  }
  // C/D layout: col(lane&15)=r index, row=quad*4+reg = x-row offset
#pragma unroll
  for (int r = 0; r < 4; r++)
    tb[(size_t)(r0 + quad * 4 + r) * 16 + m16] = f2bf(acc[r] * 2.0f);
}

// ---------------- pass 3: out = x @ W^T + t @ lora_b^T ----------------------
// 128x128 tile, BK=64, 4 waves (2x2), 4x4 16x16x32 MFMA per wave.
// LoRA delta is fused as accumulator init (K=16 zero-padded MFMA).
__global__ void lora_gemm_kernel(const unsigned short* __restrict__ xb,
                                 const unsigned short* __restrict__ wb,
                                 const unsigned short* __restrict__ tb,
                                 const unsigned short* __restrict__ lbb,
                                 float* __restrict__ out) {
  __shared__ unsigned short As[128 * 64];
  __shared__ unsigned short Bs[128 * 64];
  const int t = threadIdx.x;
  const int lane = t & 63;
  const int w = t >> 6;
  const int quad = lane >> 4;
  const int m16 = lane & 15;
  const int rowTile = blockIdx.x >> 5;   // 128 row tiles
  const int colTile = blockIdx.x & 31;   // 32 col tiles
  const int rowBase = rowTile << 7;
  const int colBase = colTile << 7;
  const int wr = w >> 1, wc = w & 1;
  const int wRow = rowBase + wr * 64;
  const int wCol = colBase + wc * 64;

  f32x4 acc[4][4];

  // ---- accumulator init = LoRA delta tile: t[128x16] @ lb[128x16]^T ----
  {
    const int a = rowBase >> 11;         // whole 128-row block is one adapter
    short8 z = {0, 0, 0, 0, 0, 0, 0, 0};
    f32x4 cz = {0.f, 0.f, 0.f, 0.f};
    short8 atf[4], btf[4];
#pragma unroll
    for (int mi = 0; mi < 4; mi++) {
      if (quad < 2)   // k=quad*8+j < 16 valid, upper half zero-padded
        atf[mi] = *(const short8*)(tb + (size_t)(wRow + mi * 16 + m16) * 16 + quad * 8);
      else
        atf[mi] = z;
    }
#pragma unroll
    for (int ni = 0; ni < 4; ni++) {
      if (quad < 2)
        btf[ni] = *(const short8*)(lbb + ((size_t)a * 4096 + (wCol + ni * 16 + m16)) * 16 + quad * 8);
      else
        btf[ni] = z;
    }
#pragma unroll
    for (int mi = 0; mi < 4; mi++)
#pragma unroll
      for (int ni = 0; ni < 4; ni++)
        acc[mi][ni] = __builtin_amdgcn_mfma_f32_16x16x32_bf16(atf[mi], btf[ni], cz, 0, 0, 0);
  }

  // ---- staging addresses: thread t loads chunk (t%8) of row (t/8)+32i ----
  const int row_s = t >> 3;              // 0..31
  const int chunk = t & 7;               // 8 x 16B chunks per 64-elem row
  const unsigned short* gA = xb + (size_t)(rowBase + row_s) * 4096 + chunk * 8;
  const unsigned short* gB = wb + (size_t)(colBase + row_s) * 4096 + chunk * 8;
  unsigned short* lA = As + t * 8;       // lane0-of-wave value = wave base
  unsigned short* lB = Bs + t * 8;

  for (int k0 = 0; k0 < 4096; k0 += 64) {
#pragma unroll
    for (int i = 0; i < 4; i++) {
      load16(gA + (size_t)i * 32 * 4096 + k0, lA + i * 2048);
      load16(gB + (size_t)i * 32 * 4096 + k0, lB + i * 2048);
    }
    __syncthreads();   // drains vmcnt (global_load_lds) + barrier
#pragma unroll
    for (int kk = 0; kk < 64; kk += 32) {
      short8 af[4], bf[4];
#pragma unroll
      for (int mi = 0; mi < 4; mi++)
        af[mi] = *(const short8*)(As + (wr * 64 + mi * 16 + m16) * 64 + kk + quad * 8);
#pragma unroll
      for (int ni = 0; ni < 4; ni++)
        bf[ni] = *(const short8*)(Bs + (wc * 64 + ni * 16 + m16) * 64 + kk + quad * 8);
#pragma unroll
      for (int mi = 0; mi < 4; mi++)
#pragma unroll
        for (int ni = 0; ni < 4; ni++)
          acc[mi][ni] = __builtin_amdgcn_mfma_f32_16x16x32_bf16(af[mi], bf[ni], acc[mi][ni], 0, 0, 0);
    }
    __syncthreads();
  }

  // ---- epilogue: C/D layout col=lane&15, row=quad*4+reg; fp32 store ----
#pragma unroll
  for (int mi = 0; mi < 4; mi++) {
    const int row0 = wRow + mi * 16 + quad * 4;
#pragma unroll
    for (int ni = 0; ni < 4; ni++) {
      const int col = wCol + ni * 16 + m16;
      float* p = out + (size_t)row0 * 4096 + col;
#pragma unroll
      for (int r = 0; r < 4; r++)
        p[(size_t)r * 4096] = acc[mi][ni][r];
    }
  }
}

extern "C" void kernel_launch(void* const* d_in, const int* in_sizes, int n_in,
                              void* d_out, int out_size, void* d_ws, size_t ws_size,
                              hipStream_t stream) {
  const float* x  = (const float*)d_in[0];   // [8,2048,4096]
  const float* W  = (const float*)d_in[1];   // [4096,4096] (out,in)
  const float* la = (const float*)d_in[2];   // [8,16,4096]
  const float* lb = (const float*)d_in[3];   // [8,4096,16]
  float* out = (float*)d_out;                // [8,2048,4096] fp32

  const size_t NX  = 8ull * 2048 * 4096;     // 67108864
  const size_t NW  = 4096ull * 4096;         // 16777216
  const size_t NT  = 16384ull * 16;          // 262144
  const size_t NLB = 8ull * 4096 * 16;       // 524288
  unsigned short* xb  = (unsigned short*)d_ws;
  unsigned short* wbf = xb + NX;
  unsigned short* tb  = wbf + NW;
  unsigned short* lbb = tb + NT;
  if (ws_size < (NX + NW + NT + NLB) * sizeof(unsigned short)) return;

  convert_kernel<<<4096, 256, 0, stream>>>(x, xb, (int)(NX / 4));
  convert_kernel<<<2048, 256, 0, stream>>>(W, wbf, (int)(NW / 4));
  convert_kernel<<<256, 256, 0, stream>>>(lb, lbb, (int)(NLB / 4));
  lora_t_kernel<<<256, 256, 0, stream>>>(xb, la, tb);
  lora_gemm_kernel<<<4096, 256, 0, stream>>>(xb, wbf, tb, lbb, out);
}